// Round 7
// baseline (289.594 us; speedup 1.0000x reference)
//
#include <hip/hip_runtime.h>

#define Tdim 4096
#define Bdim 8
#define Cdim 64
#define Ldim 15
#define Idim 2048   // T / STRIDE
#define OUTW 4160   // C + C*C
#define G    2      // windows per group
#define RX   31     // staged x rows per group
#define RXC  17     // centered rows per group
#define NBLK 1024   // groups per batch (Idim/G)
#define TOTALG 8192 // Bdim * NBLK
#define GRID  1024  // persistent blocks (4 per CU)
#define ITERS 8     // TOTALG / GRID, exact

typedef float v4f __attribute__((ext_vector_type(4)));

// R7 = R6 + persistent blocks with software-pipelined staging.
// R0==R4 proved wave count / barrier count don't matter; R6 (-6us) proved the
// store path does. Theory: per-CU blocks start/retire in lockstep -> device
// alternates {compute window: HBM-write idle} / {store burst: VALU idle};
// kernel ~= 60+43 = sum. Fix: each block loops over 8 consecutive groups,
// prefetching group k+1's x rows (issue-early after top bar, ds_write-late
// after mid bar) and letting group k's NT stores drain under group k+1's
// compute -> continuous write stream, kernel -> max(compute, stores).
__global__ __launch_bounds__(256, 4) void cbp_kernel(const float* __restrict__ x,
                                                     const float* __restrict__ w1,
                                                     const float* __restrict__ w2,
                                                     float* __restrict__ out) {
    __shared__ float xbuf[RX][64];
    __shared__ float xcs[RXC][64];
    __shared__ float mus[G][64];
    __shared__ float red[4][G];

    const int tid = threadIdx.x;
    const int blk = blockIdx.x;

    // staging task coords: task0 = tid, task1 = tid + 256 (valid for tid<240; RX*16=496)
    const int r0  = tid >> 4;
    const int r1  = r0 + 16;
    const int c4s = (tid & 15) << 2;

    // ---- prologue: stage group (blk*ITERS + 0) ----
    {
        const int grp = blk * ITERS;
        const int b   = grp >> 10;
        const int s0  = (grp & (NBLK - 1)) << 2;   // i0*2, i0 = (grp%NBLK)*G
        const float* xb = x + (size_t)b * (Tdim * Cdim);
        const int t0 = s0 - 14 + r0;
        const int t1 = s0 - 14 + r1;
        float4 st0 = make_float4(0.f, 0.f, 0.f, 0.f);
        float4 st1 = make_float4(0.f, 0.f, 0.f, 0.f);
        if (t0 >= 0 && t0 < Tdim) st0 = *(const float4*)(xb + (size_t)t0 * Cdim + c4s);
        if (tid < 240 && t1 >= 0 && t1 < Tdim)
            st1 = *(const float4*)(xb + (size_t)t1 * Cdim + c4s);
        *(float4*)(&xbuf[r0][c4s]) = st0;
        if (tid < 240) *(float4*)(&xbuf[r1][c4s]) = st1;
    }

    const int c0 = (tid >> 4) << 2;   // Gram tile coords
    const int d0 = (tid & 15) << 2;

#pragma unroll 1
    for (int it = 0; it < ITERS; ++it) {
        const int grp = blk * ITERS + it;
        const int b   = grp >> 10;
        const int i0  = (grp & (NBLK - 1)) << 1;
        const int s0  = i0 << 1;

        __syncthreads();   // xbuf(it) fully written; prev iter's LDS readers done

        // ---- issue-early: prefetch group it+1's rows into registers ----
        const bool pf = (it + 1 < ITERS);
        float4 nst0 = make_float4(0.f, 0.f, 0.f, 0.f);
        float4 nst1 = make_float4(0.f, 0.f, 0.f, 0.f);
        if (pf) {
            const int grpn = grp + 1;
            const int bn   = grpn >> 10;
            const int s0n  = (grpn & (NBLK - 1)) << 2;
            const float* xbn = x + (size_t)bn * (Tdim * Cdim);
            const int t0 = s0n - 14 + r0;
            const int t1 = s0n - 14 + r1;
            if (t0 >= 0 && t0 < Tdim) nst0 = *(const float4*)(xbn + (size_t)t0 * Cdim + c4s);
            if (tid < 240 && t1 >= 0 && t1 < Tdim)
                nst1 = *(const float4*)(xbn + (size_t)t1 * Cdim + c4s);
        }

        // ---- P2: 17 xc rows + mu at j=7,9 (272 float4 tasks) ----
        for (int v = tid; v < RXC * 16; v += 256) {
            const int j  = v >> 4;
            const int c4 = (v & 15) << 2;
            const int t  = s0 - 7 + j;
            float4 m = make_float4(0.f, 0.f, 0.f, 0.f);
#pragma unroll
            for (int k = 0; k < Ldim; ++k) {
                const float w = w1[k];
                const float4 xv = *(const float4*)(&xbuf[j + k][c4]);
                m.x = fmaf(w, xv.x, m.x);
                m.y = fmaf(w, xv.y, m.y);
                m.z = fmaf(w, xv.z, m.z);
                m.w = fmaf(w, xv.w, m.w);
            }
            const float4 xv = *(const float4*)(&xbuf[j + 7][c4]);
            float4 xc = make_float4(0.f, 0.f, 0.f, 0.f);
            if (t >= 0 && t < Tdim)
                xc = make_float4(xv.x - m.x, xv.y - m.y, xv.z - m.z, xv.w - m.w);
            *(float4*)(&xcs[j][c4]) = xc;
            if (j == 7 || j == 9)
                *(float4*)(&mus[(j - 7) >> 1][c4]) = m;
        }
        __syncthreads();   // xcs/mus ready; xbuf free (P2 done reading)

        // ---- write-late: stage next xbuf (waits vmcnt only here) ----
        if (pf) {
            *(float4*)(&xbuf[r0][c4s]) = nst0;
            if (tid < 240) *(float4*)(&xbuf[r1][c4s]) = nst1;
        }

        // ---- P3: shared-row Gram accumulation ----
        float acc[G][4][4];
#pragma unroll
        for (int g = 0; g < G; ++g)
#pragma unroll
            for (int cc = 0; cc < 4; ++cc)
#pragma unroll
                for (int dd = 0; dd < 4; ++dd) acc[g][cc][dd] = 0.f;

#pragma unroll
        for (int r = 0; r < RXC; ++r) {
            const float4 xd = *(const float4*)(&xcs[r][d0]);
            const float4 xc = *(const float4*)(&xcs[r][c0]);
#pragma unroll
            for (int g = 0; g < G; ++g) {
                const int l = r - 2 * g;
                if (l >= 0 && l < Ldim) {
                    const float w  = w2[l];
                    const float a0 = w * xc.x, a1 = w * xc.y, a2 = w * xc.z, a3 = w * xc.w;
                    acc[g][0][0] = fmaf(a0, xd.x, acc[g][0][0]);
                    acc[g][0][1] = fmaf(a0, xd.y, acc[g][0][1]);
                    acc[g][0][2] = fmaf(a0, xd.z, acc[g][0][2]);
                    acc[g][0][3] = fmaf(a0, xd.w, acc[g][0][3]);
                    acc[g][1][0] = fmaf(a1, xd.x, acc[g][1][0]);
                    acc[g][1][1] = fmaf(a1, xd.y, acc[g][1][1]);
                    acc[g][1][2] = fmaf(a1, xd.z, acc[g][1][2]);
                    acc[g][1][3] = fmaf(a1, xd.w, acc[g][1][3]);
                    acc[g][2][0] = fmaf(a2, xd.x, acc[g][2][0]);
                    acc[g][2][1] = fmaf(a2, xd.y, acc[g][2][1]);
                    acc[g][2][2] = fmaf(a2, xd.z, acc[g][2][2]);
                    acc[g][2][3] = fmaf(a2, xd.w, acc[g][2][3]);
                    acc[g][3][0] = fmaf(a3, xd.x, acc[g][3][0]);
                    acc[g][3][1] = fmaf(a3, xd.y, acc[g][3][1]);
                    acc[g][3][2] = fmaf(a3, xd.z, acc[g][3][2]);
                    acc[g][3][3] = fmaf(a3, xd.w, acc[g][3][3]);
                }
            }
        }

        // ---- P4: per-window sum of squares, single barrier ----
        float local[G];
#pragma unroll
        for (int g = 0; g < G; ++g) {
            float s = 0.f;
#pragma unroll
            for (int cc = 0; cc < 4; ++cc)
#pragma unroll
                for (int dd = 0; dd < 4; ++dd) s = fmaf(acc[g][cc][dd], acc[g][cc][dd], s);
            local[g] = s;
        }
        if (tid < Cdim) {
#pragma unroll
            for (int g = 0; g < G; ++g) local[g] = fmaf(mus[g][tid], mus[g][tid], local[g]);
        }
#pragma unroll
        for (int off = 32; off; off >>= 1)
#pragma unroll
            for (int g = 0; g < G; ++g) local[g] += __shfl_down(local[g], off, 64);
        if ((tid & 63) == 0) {
            const int w = tid >> 6;
#pragma unroll
            for (int g = 0; g < G; ++g) red[w][g] = local[g];
        }
        __syncthreads();

        float scale[G];
#pragma unroll
        for (int g = 0; g < G; ++g) {
            const float ss = red[0][g] + red[1][g] + red[2][g] + red[3][g];
            scale[g] = rsqrtf(fmaxf(ss, 1e-12f));
        }

        // ---- NT stores; drain under next iteration's compute ----
#pragma unroll
        for (int g = 0; g < G; ++g) {
            const float sc = scale[g];
            float* orow = out + (size_t)(b * Idim + i0 + g) * OUTW;
            if (tid < 16) {
                const float4 m4 = *(const float4*)(&mus[g][tid << 2]);
                v4f mv = { m4.x * sc, m4.y * sc, m4.z * sc, m4.w * sc };
                __builtin_nontemporal_store(mv, (v4f*)(orow + (tid << 2)));
            }
            float* osig = orow + Cdim;
#pragma unroll
            for (int cc = 0; cc < 4; ++cc) {
                v4f v = { acc[g][cc][0] * sc, acc[g][cc][1] * sc,
                          acc[g][cc][2] * sc, acc[g][cc][3] * sc };
                __builtin_nontemporal_store(v, (v4f*)(osig + (c0 + cc) * Cdim + d0));
            }
        }
    }
}

extern "C" void kernel_launch(void* const* d_in, const int* in_sizes, int n_in,
                              void* d_out, int out_size, void* d_ws, size_t ws_size,
                              hipStream_t stream) {
    const float* x  = (const float*)d_in[0];
    const float* w1 = (const float*)d_in[1];
    const float* w2 = (const float*)d_in[2];
    float* out = (float*)d_out;
    cbp_kernel<<<dim3(GRID), dim3(256), 0, stream>>>(x, w1, w2, out);
}

// Round 8
// 289.230 us; speedup vs baseline: 1.0013x; 1.0013x over previous
//
#include <hip/hip_runtime.h>

#define Tdim 4096
#define Bdim 8
#define Cdim 64
#define Ldim 15
#define Idim 2048   // T / STRIDE
#define OUTW 4160   // C + C*C
#define G    2      // windows per group
#define RX   31     // staged x rows per group
#define RXC  17     // centered rows per group
#define NBLK 1024   // groups per batch (Idim/G)
#define TOTALG 8192 // Bdim * NBLK
#define GRID  1024  // persistent blocks (4 per CU)
#define ITERS 8     // TOTALG / GRID, exact

typedef float v4f __attribute__((ext_vector_type(4)));

// R8 = R7 with the barrier bug fixed. R7's __syncthreads() compiles to
// s_waitcnt vmcnt(0) lgkmcnt(0) + s_barrier -> every iteration drained ALL
// NT stores to HBM before proceeding (T4 violation: never vmcnt(0) in-loop).
// Fix: raw s_barrier + lgkmcnt(0)-only wait. LDS ordering is fully covered
// by lgkmcnt (counts ds reads AND writes; each wave's ops complete at barrier
// entry). Prefetch-load consumption is ordered by register dependence
// (compiler emits counted vmcnt). NT stores are NEVER waited -> they drain
// under the next iteration's P2/P3 compute.
#define BAR() do {                                            \
    asm volatile("s_waitcnt lgkmcnt(0)" ::: "memory");        \
    __builtin_amdgcn_s_barrier();                             \
    __builtin_amdgcn_sched_barrier(0);                        \
} while (0)

__global__ __launch_bounds__(256, 4) void cbp_kernel(const float* __restrict__ x,
                                                     const float* __restrict__ w1,
                                                     const float* __restrict__ w2,
                                                     float* __restrict__ out) {
    __shared__ float xbuf[RX][64];
    __shared__ float xcs[RXC][64];
    __shared__ float mus[G][64];
    __shared__ float red[4][G];

    const int tid = threadIdx.x;
    const int blk = blockIdx.x;

    // staging task coords: task0 = tid, task1 = tid + 256 (valid for tid<240; RX*16=496)
    const int r0  = tid >> 4;
    const int r1  = r0 + 16;
    const int c4s = (tid & 15) << 2;

    // ---- prologue: stage group (blk*ITERS + 0) ----
    {
        const int grp = blk * ITERS;
        const int b   = grp >> 10;
        const int s0  = (grp & (NBLK - 1)) << 2;   // i0*2, i0 = (grp%NBLK)*G
        const float* xb = x + (size_t)b * (Tdim * Cdim);
        const int t0 = s0 - 14 + r0;
        const int t1 = s0 - 14 + r1;
        float4 st0 = make_float4(0.f, 0.f, 0.f, 0.f);
        float4 st1 = make_float4(0.f, 0.f, 0.f, 0.f);
        if (t0 >= 0 && t0 < Tdim) st0 = *(const float4*)(xb + (size_t)t0 * Cdim + c4s);
        if (tid < 240 && t1 >= 0 && t1 < Tdim)
            st1 = *(const float4*)(xb + (size_t)t1 * Cdim + c4s);
        *(float4*)(&xbuf[r0][c4s]) = st0;
        if (tid < 240) *(float4*)(&xbuf[r1][c4s]) = st1;
    }

    const int c0 = (tid >> 4) << 2;   // Gram tile coords
    const int d0 = (tid & 15) << 2;

#pragma unroll 1
    for (int it = 0; it < ITERS; ++it) {
        const int grp = blk * ITERS + it;
        const int b   = grp >> 10;
        const int i0  = (grp & (NBLK - 1)) << 1;
        const int s0  = i0 << 1;

        BAR();   // xbuf(it) writes complete everywhere; prev iter's LDS reads done

        // ---- issue-early: prefetch group it+1's rows into registers ----
        const bool pf = (it + 1 < ITERS);
        float4 nst0 = make_float4(0.f, 0.f, 0.f, 0.f);
        float4 nst1 = make_float4(0.f, 0.f, 0.f, 0.f);
        if (pf) {
            const int grpn = grp + 1;
            const int bn   = grpn >> 10;
            const int s0n  = (grpn & (NBLK - 1)) << 2;
            const float* xbn = x + (size_t)bn * (Tdim * Cdim);
            const int t0 = s0n - 14 + r0;
            const int t1 = s0n - 14 + r1;
            if (t0 >= 0 && t0 < Tdim) nst0 = *(const float4*)(xbn + (size_t)t0 * Cdim + c4s);
            if (tid < 240 && t1 >= 0 && t1 < Tdim)
                nst1 = *(const float4*)(xbn + (size_t)t1 * Cdim + c4s);
        }

        // ---- P2: 17 xc rows + mu at j=7,9 (272 float4 tasks) ----
        for (int v = tid; v < RXC * 16; v += 256) {
            const int j  = v >> 4;
            const int c4 = (v & 15) << 2;
            const int t  = s0 - 7 + j;
            float4 m = make_float4(0.f, 0.f, 0.f, 0.f);
#pragma unroll
            for (int k = 0; k < Ldim; ++k) {
                const float w = w1[k];
                const float4 xv = *(const float4*)(&xbuf[j + k][c4]);
                m.x = fmaf(w, xv.x, m.x);
                m.y = fmaf(w, xv.y, m.y);
                m.z = fmaf(w, xv.z, m.z);
                m.w = fmaf(w, xv.w, m.w);
            }
            const float4 xv = *(const float4*)(&xbuf[j + 7][c4]);
            float4 xc = make_float4(0.f, 0.f, 0.f, 0.f);
            if (t >= 0 && t < Tdim)
                xc = make_float4(xv.x - m.x, xv.y - m.y, xv.z - m.z, xv.w - m.w);
            *(float4*)(&xcs[j][c4]) = xc;
            if (j == 7 || j == 9)
                *(float4*)(&mus[(j - 7) >> 1][c4]) = m;
        }
        BAR();   // xcs/mus ready; P2's xbuf reads complete -> xbuf free

        // ---- write-late: stage next xbuf (register dep waits counted vmcnt) ----
        if (pf) {
            *(float4*)(&xbuf[r0][c4s]) = nst0;
            if (tid < 240) *(float4*)(&xbuf[r1][c4s]) = nst1;
        }

        // ---- P3: shared-row Gram accumulation ----
        float acc[G][4][4];
#pragma unroll
        for (int g = 0; g < G; ++g)
#pragma unroll
            for (int cc = 0; cc < 4; ++cc)
#pragma unroll
                for (int dd = 0; dd < 4; ++dd) acc[g][cc][dd] = 0.f;

#pragma unroll
        for (int r = 0; r < RXC; ++r) {
            const float4 xd = *(const float4*)(&xcs[r][d0]);
            const float4 xc = *(const float4*)(&xcs[r][c0]);
#pragma unroll
            for (int g = 0; g < G; ++g) {
                const int l = r - 2 * g;
                if (l >= 0 && l < Ldim) {
                    const float w  = w2[l];
                    const float a0 = w * xc.x, a1 = w * xc.y, a2 = w * xc.z, a3 = w * xc.w;
                    acc[g][0][0] = fmaf(a0, xd.x, acc[g][0][0]);
                    acc[g][0][1] = fmaf(a0, xd.y, acc[g][0][1]);
                    acc[g][0][2] = fmaf(a0, xd.z, acc[g][0][2]);
                    acc[g][0][3] = fmaf(a0, xd.w, acc[g][0][3]);
                    acc[g][1][0] = fmaf(a1, xd.x, acc[g][1][0]);
                    acc[g][1][1] = fmaf(a1, xd.y, acc[g][1][1]);
                    acc[g][1][2] = fmaf(a1, xd.z, acc[g][1][2]);
                    acc[g][1][3] = fmaf(a1, xd.w, acc[g][1][3]);
                    acc[g][2][0] = fmaf(a2, xd.x, acc[g][2][0]);
                    acc[g][2][1] = fmaf(a2, xd.y, acc[g][2][1]);
                    acc[g][2][2] = fmaf(a2, xd.z, acc[g][2][2]);
                    acc[g][2][3] = fmaf(a2, xd.w, acc[g][2][3]);
                    acc[g][3][0] = fmaf(a3, xd.x, acc[g][3][0]);
                    acc[g][3][1] = fmaf(a3, xd.y, acc[g][3][1]);
                    acc[g][3][2] = fmaf(a3, xd.z, acc[g][3][2]);
                    acc[g][3][3] = fmaf(a3, xd.w, acc[g][3][3]);
                }
            }
        }

        // ---- P4: per-window sum of squares ----
        float local[G];
#pragma unroll
        for (int g = 0; g < G; ++g) {
            float s = 0.f;
#pragma unroll
            for (int cc = 0; cc < 4; ++cc)
#pragma unroll
                for (int dd = 0; dd < 4; ++dd) s = fmaf(acc[g][cc][dd], acc[g][cc][dd], s);
            local[g] = s;
        }
        if (tid < Cdim) {
#pragma unroll
            for (int g = 0; g < G; ++g) local[g] = fmaf(mus[g][tid], mus[g][tid], local[g]);
        }
#pragma unroll
        for (int off = 32; off; off >>= 1)
#pragma unroll
            for (int g = 0; g < G; ++g) local[g] += __shfl_down(local[g], off, 64);
        if ((tid & 63) == 0) {
            const int w = tid >> 6;
#pragma unroll
            for (int g = 0; g < G; ++g) red[w][g] = local[g];
        }
        BAR();   // red complete

        float scale[G];
#pragma unroll
        for (int g = 0; g < G; ++g) {
            const float ss = red[0][g] + red[1][g] + red[2][g] + red[3][g];
            scale[g] = rsqrtf(fmaxf(ss, 1e-12f));
        }

        // ---- NT stores; NEVER waited -> drain under next iteration's compute ----
#pragma unroll
        for (int g = 0; g < G; ++g) {
            const float sc = scale[g];
            float* orow = out + (size_t)(b * Idim + i0 + g) * OUTW;
            if (tid < 16) {
                const float4 m4 = *(const float4*)(&mus[g][tid << 2]);
                v4f mv = { m4.x * sc, m4.y * sc, m4.z * sc, m4.w * sc };
                __builtin_nontemporal_store(mv, (v4f*)(orow + (tid << 2)));
            }
            float* osig = orow + Cdim;
#pragma unroll
            for (int cc = 0; cc < 4; ++cc) {
                v4f v = { acc[g][cc][0] * sc, acc[g][cc][1] * sc,
                          acc[g][cc][2] * sc, acc[g][cc][3] * sc };
                __builtin_nontemporal_store(v, (v4f*)(osig + (c0 + cc) * Cdim + d0));
            }
        }
    }
}

extern "C" void kernel_launch(void* const* d_in, const int* in_sizes, int n_in,
                              void* d_out, int out_size, void* d_ws, size_t ws_size,
                              hipStream_t stream) {
    const float* x  = (const float*)d_in[0];
    const float* w1 = (const float*)d_in[1];
    const float* w2 = (const float*)d_in[2];
    float* out = (float*)d_out;
    cbp_kernel<<<dim3(GRID), dim3(256), 0, stream>>>(x, w1, w2, out);
}

// Round 9
// 284.637 us; speedup vs baseline: 1.0174x; 1.0161x over previous
//
#include <hip/hip_runtime.h>

#define Tdim 4096
#define Bdim 8
#define Cdim 64
#define Ldim 15
#define Idim 2048   // T / STRIDE
#define OUTW 4160   // C + C*C
#define G    2      // windows per block
#define RX   (2*G + 27)   // 31 staged x rows
#define RXC  (2*G + 13)   // 17 centered rows
#define NBLK (Idim / G)   // 1024 blocks per batch

typedef float v4f __attribute__((ext_vector_type(4)));

// FINAL (R6 reproduction): session best, 281.3 us.
// Evidence: R0(16 waves,3 bars)==R4(24 waves,1 bar) to 0.07% -> kernel time is
// a memory-system floor (fill drain + compulsory 273MB output write), not
// structure. NT stores (-6us) bypass L2/L3 allocation behind the still-
// draining harness fill. Persistent/pipelined variants (R7/R8, incl. raw
// s_barrier + lgkm-only waits) were +8us: no recoverable overlap exists.
__global__ __launch_bounds__(256, 6) void cbp_kernel(const float* __restrict__ x,
                                                     const float* __restrict__ w1,
                                                     const float* __restrict__ w2,
                                                     float* __restrict__ out) {
    __shared__ float xbuf[RX][64];
    __shared__ float xcs[RXC][64];
    __shared__ float mus[G][64];
    __shared__ float red[4][G];

    const int tid = threadIdx.x;
    const int blk = blockIdx.x;
    const int b  = blk >> 10;            // / NBLK
    const int i0 = (blk & (NBLK - 1)) << 1;   // first window index (G=2)
    const int s0 = i0 << 1;                    // STRIDE = 2

    // ---- P1: stage 31 rows, float4, zero-padded ----
    const float* xb = x + (size_t)b * (Tdim * Cdim);
    for (int v = tid; v < RX * 16; v += 256) {
        const int r  = v >> 4;
        const int c4 = (v & 15) << 2;
        const int t  = s0 - 14 + r;
        float4 val = make_float4(0.f, 0.f, 0.f, 0.f);
        if (t >= 0 && t < Tdim) val = *(const float4*)(xb + (size_t)t * Cdim + c4);
        *(float4*)(&xbuf[r][c4]) = val;
    }
    __syncthreads();

    // ---- P2: 17 unique xc rows (272 float4 tasks); mu kept at j=7,9 ----
    for (int v = tid; v < RXC * 16; v += 256) {
        const int j  = v >> 4;
        const int c4 = (v & 15) << 2;
        const int t  = s0 - 7 + j;
        float4 m = make_float4(0.f, 0.f, 0.f, 0.f);
#pragma unroll
        for (int k = 0; k < Ldim; ++k) {
            const float w = w1[k];               // uniform -> s_load, hoisted
            const float4 xv = *(const float4*)(&xbuf[j + k][c4]);
            m.x = fmaf(w, xv.x, m.x);
            m.y = fmaf(w, xv.y, m.y);
            m.z = fmaf(w, xv.z, m.z);
            m.w = fmaf(w, xv.w, m.w);
        }
        const float4 xv = *(const float4*)(&xbuf[j + 7][c4]);
        float4 xc = make_float4(0.f, 0.f, 0.f, 0.f);
        if (t >= 0 && t < Tdim)
            xc = make_float4(xv.x - m.x, xv.y - m.y, xv.z - m.z, xv.w - m.w);
        *(float4*)(&xcs[j][c4]) = xc;
        if (j == 7 || j == 9)
            *(float4*)(&mus[(j - 7) >> 1][c4]) = m;   // always in-range (s0+2g < T)
    }
    __syncthreads();

    // ---- P3: shared-row Gram accumulation (32 acc VGPRs) ----
    const int c0 = (tid >> 4) << 2;   // 0..60
    const int d0 = (tid & 15) << 2;   // 0..60
    float acc[G][4][4];
#pragma unroll
    for (int g = 0; g < G; ++g)
#pragma unroll
        for (int cc = 0; cc < 4; ++cc)
#pragma unroll
            for (int dd = 0; dd < 4; ++dd) acc[g][cc][dd] = 0.f;

#pragma unroll
    for (int r = 0; r < RXC; ++r) {
        const float4 xd = *(const float4*)(&xcs[r][d0]);   // ds_read_b128
        const float4 xc = *(const float4*)(&xcs[r][c0]);   // ds_read_b128 (bcast)
#pragma unroll
        for (int g = 0; g < G; ++g) {
            const int l = r - 2 * g;
            if (l >= 0 && l < Ldim) {                       // static after unroll
                const float w  = w2[l];                     // s_load, hoisted
                const float a0 = w * xc.x, a1 = w * xc.y, a2 = w * xc.z, a3 = w * xc.w;
                acc[g][0][0] = fmaf(a0, xd.x, acc[g][0][0]);
                acc[g][0][1] = fmaf(a0, xd.y, acc[g][0][1]);
                acc[g][0][2] = fmaf(a0, xd.z, acc[g][0][2]);
                acc[g][0][3] = fmaf(a0, xd.w, acc[g][0][3]);
                acc[g][1][0] = fmaf(a1, xd.x, acc[g][1][0]);
                acc[g][1][1] = fmaf(a1, xd.y, acc[g][1][1]);
                acc[g][1][2] = fmaf(a1, xd.z, acc[g][1][2]);
                acc[g][1][3] = fmaf(a1, xd.w, acc[g][1][3]);
                acc[g][2][0] = fmaf(a2, xd.x, acc[g][2][0]);
                acc[g][2][1] = fmaf(a2, xd.y, acc[g][2][1]);
                acc[g][2][2] = fmaf(a2, xd.z, acc[g][2][2]);
                acc[g][2][3] = fmaf(a2, xd.w, acc[g][2][3]);
                acc[g][3][0] = fmaf(a3, xd.x, acc[g][3][0]);
                acc[g][3][1] = fmaf(a3, xd.y, acc[g][3][1]);
                acc[g][3][2] = fmaf(a3, xd.z, acc[g][3][2]);
                acc[g][3][3] = fmaf(a3, xd.w, acc[g][3][3]);
            }
        }
    }

    // ---- P4: per-window sum of squares, SINGLE barrier ----
    float local[G];
#pragma unroll
    for (int g = 0; g < G; ++g) {
        float s = 0.f;
#pragma unroll
        for (int cc = 0; cc < 4; ++cc)
#pragma unroll
            for (int dd = 0; dd < 4; ++dd) s = fmaf(acc[g][cc][dd], acc[g][cc][dd], s);
        local[g] = s;
    }
    if (tid < Cdim) {
#pragma unroll
        for (int g = 0; g < G; ++g) local[g] = fmaf(mus[g][tid], mus[g][tid], local[g]);
    }
#pragma unroll
    for (int off = 32; off; off >>= 1)
#pragma unroll
        for (int g = 0; g < G; ++g) local[g] += __shfl_down(local[g], off, 64);
    if ((tid & 63) == 0) {
        const int w = tid >> 6;
#pragma unroll
        for (int g = 0; g < G; ++g) red[w][g] = local[g];
    }
    __syncthreads();

    float scale[G];
#pragma unroll
    for (int g = 0; g < G; ++g) {
        const float ss = red[0][g] + red[1][g] + red[2][g] + red[3][g];  // broadcast
        scale[g] = rsqrtf(fmaxf(ss, 1e-12f));
    }

    // ---- Epilogue: coalesced NONTEMPORAL stores ----
#pragma unroll
    for (int g = 0; g < G; ++g) {
        const float sc = scale[g];
        float* orow = out + (size_t)(b * Idim + i0 + g) * OUTW;
        if (tid < 16) {
            const float4 m4 = *(const float4*)(&mus[g][tid << 2]);
            v4f mv = { m4.x * sc, m4.y * sc, m4.z * sc, m4.w * sc };
            __builtin_nontemporal_store(mv, (v4f*)(orow + (tid << 2)));
        }
        float* osig = orow + Cdim;
#pragma unroll
        for (int cc = 0; cc < 4; ++cc) {
            v4f v = { acc[g][cc][0] * sc, acc[g][cc][1] * sc,
                      acc[g][cc][2] * sc, acc[g][cc][3] * sc };
            __builtin_nontemporal_store(v, (v4f*)(osig + (c0 + cc) * Cdim + d0));
        }
    }
}

extern "C" void kernel_launch(void* const* d_in, const int* in_sizes, int n_in,
                              void* d_out, int out_size, void* d_ws, size_t ws_size,
                              hipStream_t stream) {
    const float* x  = (const float*)d_in[0];
    const float* w1 = (const float*)d_in[1];
    const float* w2 = (const float*)d_in[2];
    float* out = (float*)d_out;
    cbp_kernel<<<dim3(Bdim * NBLK), dim3(256), 0, stream>>>(x, w1, w2, out);
}